// Round 3
// baseline (525.222 us; speedup 1.0000x reference)
//
#include <hip/hip_runtime.h>

#define NSEQ 512
#define RTOT (NSEQ*NSEQ)   // 262144 rows
#define DM 128

typedef unsigned short ushort_t;
using short8 = __attribute__((ext_vector_type(8))) short;
using f32x4  = __attribute__((ext_vector_type(4))) float;

__device__ __forceinline__ unsigned short f2bf(float x){
  union { float f; unsigned int u; } v; v.f = x;
  unsigned int r = v.u + 0x7fffu + ((v.u >> 16) & 1u);   // RNE
  return (unsigned short)(r >> 16);
}
__device__ __forceinline__ float bf2f(unsigned short u){
  union { unsigned int u; float f; } v; v.u = ((unsigned int)u) << 16;
  return v.f;
}
__device__ __forceinline__ unsigned int pack2(float a, float b){
  return (unsigned int)f2bf(a) | ((unsigned int)f2bf(b) << 16);
}
__device__ __forceinline__ float sigmoidf(float x){ return 1.0f/(1.0f + __expf(-x)); }

// -------- K_prep: one-shot fp32 -> bf16 conversion of k1 weights -----------
__global__ __launch_bounds__(256) void k_prep(const float* __restrict__ a,
                                              const float* __restrict__ b,
                                              ushort_t* __restrict__ da,
                                              ushort_t* __restrict__ db,
                                              int na4, int nb4){
  int idx = blockIdx.x*256 + threadIdx.x;
  const float* src; ushort_t* dst; int i;
  if (idx < na4){ src = a; dst = da; i = idx; }
  else { i = idx - na4; if (i >= nb4) return; src = b; dst = db; }
  float4 v = *(const float4*)(src + (size_t)i*4);
  uint2 pk; pk.x = pack2(v.x, v.y); pk.y = pack2(v.z, v.w);
  *(uint2*)(dst + (size_t)i*4) = pk;
}

// -------- K_prep2: k3 weights. W'[h,d]=ln_out_w[d]*p_out_w[h,d] (bf16);
// c1[h]=sum_d bf16(W'); c2[h]=sum_d ln_out_b[d]*p_out_w[h,d]; wg = bf16(g_out_w).
__global__ __launch_bounds__(256) void k_prep2(const float* __restrict__ p_out_w,
                                               const float* __restrict__ g_out_w,
                                               const float* __restrict__ ln_out_w,
                                               const float* __restrict__ ln_out_b,
                                               ushort_t* __restrict__ wp,
                                               ushort_t* __restrict__ wg,
                                               float2* __restrict__ c12){
  int t = threadIdx.x;
  if (t < 128){
    float s1 = 0.f, s2 = 0.f;
    for (int d = 0; d < DM; d++){
      float v = p_out_w[(size_t)t*DM + d];
      unsigned short h = f2bf(v * ln_out_w[d]);
      wp[(size_t)t*DM + d] = h;
      s1 += bf2f(h);
      s2 += ln_out_b[d] * v;
    }
    c12[t] = make_float2(s1, s2);
  } else {
    int r = t - 128;
    for (int d = 0; d < DM; d += 4){
      float4 v = *(const float4*)&g_out_w[(size_t)r*DM + d];
      uint2 pk; pk.x = pack2(v.x, v.y); pk.y = pack2(v.z, v.w);
      *(uint2*)&wg[(size_t)r*DM + d] = pk;
    }
  }
}

// ---------------- K0: LayerNorm(pair) -> lnx bf16 [R][128] -----------------
__global__ __launch_bounds__(256) void k0_ln_in(const float* __restrict__ pair,
                                                const float* __restrict__ w,
                                                const float* __restrict__ b,
                                                ushort_t* __restrict__ lnx){
  int wv = threadIdx.x >> 6, lane = threadIdx.x & 63;
  size_t row = (size_t)blockIdx.x * 4 + wv;          // one wave per row
  const float2* src = (const float2*)(pair + row * DM);
  float2 v = src[lane];
  float s = v.x + v.y, s2 = v.x*v.x + v.y*v.y;
  #pragma unroll
  for (int off = 32; off; off >>= 1){ s += __shfl_xor(s, off); s2 += __shfl_xor(s2, off); }
  float mu = s * (1.f/DM);
  float rstd = rsqrtf(s2*(1.f/DM) - mu*mu + 1e-5f);
  float o0 = (v.x - mu)*rstd*w[2*lane]   + b[2*lane];
  float o1 = (v.y - mu)*rstd*w[2*lane+1] + b[2*lane+1];
  ((unsigned int*)(lnx + row * DM))[lane] = pack2(o0, o1);
}

// ------ K1: no-LDS in-proj. Wave wc handles 16 paired p/g cols; b-frags
// hoisted to VGPRs once; a-frags direct global uint4 (L1-shared by 4 waves);
// 4x64-row chunks per block. Output d-major [128][RTOT].
__global__ __launch_bounds__(256) void k1_inproj(const ushort_t* __restrict__ lnx,
                                                 const ushort_t* __restrict__ pw_bf,
                                                 const ushort_t* __restrict__ gw_bf,
                                                 ushort_t* __restrict__ left,
                                                 ushort_t* __restrict__ right){
  int tid = threadIdx.x;
  int wc = tid >> 6, lane = tid & 63, m = lane & 15, quad = lane >> 4;
  int job = blockIdx.x;                 // 0..3
  int wrow0 = ((job >= 2) ? 128 : 0) + (job & 1) * 64;
  ushort_t* outp = (job >= 2) ? right : left;
  int d = (job & 1) * 64 + wc*16 + m;
  size_t row0 = (size_t)blockIdx.y * 256;

  const ushort_t* prow = pw_bf + (size_t)(wrow0 + wc*16 + m)*DM + quad*8;
  const ushort_t* grow = gw_bf + (size_t)(wrow0 + wc*16 + m)*DM + quad*8;
  short8 bp[4], bg[4];
  #pragma unroll
  for (int k = 0; k < 4; k++){
    bp[k] = *(const short8*)(prow + k*32);
    bg[k] = *(const short8*)(grow + k*32);
  }

  #pragma unroll
  for (int ch = 0; ch < 4; ch++){
    size_t r0 = row0 + ch*64;
    f32x4 accp[4], accg[4];
    #pragma unroll
    for (int i = 0; i < 4; i++){ accp[i] = (f32x4){0.f,0.f,0.f,0.f}; accg[i] = (f32x4){0.f,0.f,0.f,0.f}; }
    #pragma unroll
    for (int k = 0; k < 4; k++){
      #pragma unroll
      for (int rt = 0; rt < 4; rt++){
        short8 a = *(const short8*)&lnx[(r0 + rt*16 + m)*DM + k*32 + quad*8];
        accp[rt] = __builtin_amdgcn_mfma_f32_16x16x32_bf16(a, bp[k], accp[rt], 0, 0, 0);
        accg[rt] = __builtin_amdgcn_mfma_f32_16x16x32_bf16(a, bg[k], accg[rt], 0, 0, 0);
      }
    }
    #pragma unroll
    for (int rt = 0; rt < 4; rt++){
      uint2 pk;
      pk.x = pack2(sigmoidf(accg[rt][0])*accp[rt][0], sigmoidf(accg[rt][1])*accp[rt][1]);
      pk.y = pack2(sigmoidf(accg[rt][2])*accp[rt][2], sigmoidf(accg[rt][3])*accp[rt][3]);
      *(uint2*)&outp[(size_t)d * RTOT + r0 + rt*16 + quad*4] = pk;
    }
  }
}

// ------- K2: per d-plane NT GEMM: tri[d][i][j] = sum_k L[i,k]R[j,k]/L ------
__global__ __launch_bounds__(256) void k2_tri(const ushort_t* __restrict__ left,
                                              const ushort_t* __restrict__ right,
                                              ushort_t* __restrict__ tri){
  __shared__ __align__(16) ushort_t As[128][72];
  __shared__ __align__(16) ushort_t Bs[128][72];
  int tid = threadIdx.x;
  int b = blockIdx.x;
  int d = b & 127, ti = b >> 7;
  const ushort_t* Ap = left  + (size_t)d * RTOT;
  const ushort_t* Bp = right + (size_t)d * RTOT;
  ushort_t* Cp = tri + (size_t)d * RTOT;
  int i0 = ti * 128;
  int w = tid >> 6, lane = tid & 63, m = lane & 15, quad = lane >> 4;
  int wr = w & 1, wc = w >> 1;

  for (int tj = 0; tj < 4; tj++){
    int j0 = tj * 128;
    f32x4 acc[16];
    #pragma unroll
    for (int x = 0; x < 16; x++) acc[x] = (f32x4){0.f,0.f,0.f,0.f};

    for (int kt = 0; kt < NSEQ; kt += 64){
      __syncthreads();
      #pragma unroll
      for (int it = 0; it < 4; it++){
        int e = (tid + it*256) * 8; int r = e >> 6, c = e & 63;
        *(uint4*)&As[r][c] = *(const uint4*)&Ap[(size_t)(i0 + r)*NSEQ + kt + c];
        *(uint4*)&Bs[r][c] = *(const uint4*)&Bp[(size_t)(j0 + r)*NSEQ + kt + c];
      }
      __syncthreads();
      #pragma unroll
      for (int kk = 0; kk < 64; kk += 32){
        short8 a[4], bb[4];
        #pragma unroll
        for (int t = 0; t < 4; t++) a[t]  = *(const short8*)&As[wr*64 + t*16 + m][kk + quad*8];
        #pragma unroll
        for (int c = 0; c < 4; c++) bb[c] = *(const short8*)&Bs[wc*64 + c*16 + m][kk + quad*8];
        #pragma unroll
        for (int t = 0; t < 4; t++){
          #pragma unroll
          for (int c = 0; c < 4; c++){
            acc[t*4+c] = __builtin_amdgcn_mfma_f32_16x16x32_bf16(a[t], bb[c], acc[t*4+c], 0, 0, 0);
          }
        }
      }
    }
    const float s = 1.f / (float)NSEQ;
    #pragma unroll
    for (int t = 0; t < 4; t++){
      #pragma unroll
      for (int c = 0; c < 4; c++){
        int col = j0 + wc*64 + c*16 + m;
        #pragma unroll
        for (int rr = 0; rr < 4; rr++){
          int row = i0 + wr*64 + t*16 + quad*4 + rr;
          Cp[(size_t)row * NSEQ + col] = f2bf(acc[t*4+c][rr] * s);
        }
      }
    }
  }
}

// --- K3: transpose tri^T chunk into LDS (stats in-flight), folded-LN GEMM
//     with W', plus gate GEMM on direct-global lnx frags. --------------------
__global__ __launch_bounds__(256) void k3_out(const ushort_t* __restrict__ tri,
                                              const ushort_t* __restrict__ lnx,
                                              const ushort_t* __restrict__ wp,
                                              const ushort_t* __restrict__ wg,
                                              const float2* __restrict__ c12,
                                              float* __restrict__ out){
  __shared__ __align__(16) ushort_t A1[64][136];   // raw tri^T rows
  __shared__ __align__(16) ushort_t Bt[64][136];   // weight chunk
  __shared__ float ss[64][4], sq[64][4];
  __shared__ float2 srow[64];
  __shared__ float2 c12s[128];
  int tid = threadIdx.x;
  size_t r0 = (size_t)blockIdx.x * 64;
  if (tid < 128) c12s[tid] = c12[tid];

  int j = tid & 63, wv = tid >> 6;
  {                                                // transpose + stats accumulate
    float fs = 0.f, fq = 0.f;
    #pragma unroll
    for (int g = 0; g < 4; g++){
      int oct = wv*4 + g;
      const ushort_t* src = tri + (size_t)(oct*8)*RTOT + r0 + j;
      short8 v;
      #pragma unroll
      for (int dd = 0; dd < 8; dd++){
        unsigned short u = src[(size_t)dd * RTOT];
        v[dd] = (short)u;
        float f = bf2f(u); fs += f; fq += f*f;
      }
      *(short8*)&A1[j][oct*8] = v;
    }
    ss[j][wv] = fs; sq[j][wv] = fq;
  }
  __syncthreads();
  if (tid < 64){
    float s = ss[tid][0]+ss[tid][1]+ss[tid][2]+ss[tid][3];
    float q = sq[tid][0]+sq[tid][1]+sq[tid][2]+sq[tid][3];
    float mu = s * (1.f/DM);
    float rstd = rsqrtf(q*(1.f/DM) - mu*mu + 1e-5f);
    srow[tid] = make_float2(mu, rstd);
  }
  __syncthreads();

  int lane = tid & 63, m = lane & 15, quad = lane >> 4;
  short8 a1[4], a2[4];
  #pragma unroll
  for (int k = 0; k < 4; k++){
    a1[k] = *(const short8*)&A1[wv*16 + m][k*32 + quad*8];
    a2[k] = *(const short8*)&lnx[(r0 + wv*16 + m)*DM + k*32 + quad*8];
  }
  float2 st[4];
  #pragma unroll
  for (int rr = 0; rr < 4; rr++) st[rr] = srow[wv*16 + quad*4 + rr];

  #pragma unroll
  for (int ch = 0; ch < 2; ch++){
    f32x4 accp[4], accg[4];
    #pragma unroll
    for (int i = 0; i < 4; i++){ accp[i] = (f32x4){0.f,0.f,0.f,0.f}; accg[i] = (f32x4){0.f,0.f,0.f,0.f}; }

    #pragma unroll
    for (int it = 0; it < 4; it++){                // Bt <- W' rows
      int e = (tid + it*256) * 8; int r = e >> 7, c = e & 127;
      *(uint4*)&Bt[r][c] = *(const uint4*)&wp[(size_t)(ch*64 + r)*DM + c];
    }
    __syncthreads();
    #pragma unroll
    for (int k = 0; k < 4; k++){
      #pragma unroll
      for (int c = 0; c < 4; c++){
        short8 bf = *(const short8*)&Bt[c*16 + m][k*32 + quad*8];
        accp[c] = __builtin_amdgcn_mfma_f32_16x16x32_bf16(a1[k], bf, accp[c], 0, 0, 0);
      }
    }
    __syncthreads();
    #pragma unroll
    for (int it = 0; it < 4; it++){                // Bt <- g_out rows
      int e = (tid + it*256) * 8; int r = e >> 7, c = e & 127;
      *(uint4*)&Bt[r][c] = *(const uint4*)&wg[(size_t)(ch*64 + r)*DM + c];
    }
    __syncthreads();
    #pragma unroll
    for (int k = 0; k < 4; k++){
      #pragma unroll
      for (int c = 0; c < 4; c++){
        short8 bf = *(const short8*)&Bt[c*16 + m][k*32 + quad*8];
        accg[c] = __builtin_amdgcn_mfma_f32_16x16x32_bf16(a2[k], bf, accg[c], 0, 0, 0);
      }
    }
    #pragma unroll
    for (int c = 0; c < 4; c++){
      int h = ch*64 + c*16 + m;
      float2 cc = c12s[h];
      #pragma unroll
      for (int rr = 0; rr < 4; rr++){
        float val = st[rr].y * (accp[c][rr] - st[rr].x * cc.x) + cc.y;
        out[(r0 + wv*16 + quad*4 + rr)*DM + h] = sigmoidf(accg[c][rr]) * val;
      }
    }
    __syncthreads();                               // protect Bt for next chunk
  }
}

extern "C" void kernel_launch(void* const* d_in, const int* in_sizes, int n_in,
                              void* d_out, int out_size, void* d_ws, size_t ws_size,
                              hipStream_t stream){
  const float* pair     = (const float*)d_in[0];
  const float* ln_in_w  = (const float*)d_in[1];
  const float* ln_in_b  = (const float*)d_in[2];
  const float* p_in_w   = (const float*)d_in[3];
  const float* g_in_w   = (const float*)d_in[4];
  const float* ln_out_w = (const float*)d_in[5];
  const float* ln_out_b = (const float*)d_in[6];
  const float* p_out_w  = (const float*)d_in[7];
  const float* g_out_w  = (const float*)d_in[8];
  float* out = (float*)d_out;

  const size_t plane = (size_t)RTOT * DM;          // 33.5M elems, 64 MB bf16
  ushort_t* lnx   = (ushort_t*)d_ws;
  ushort_t* left  = lnx   + plane;
  ushort_t* right = left  + plane;
  ushort_t* tri   = right + plane;                 // total 256 MB

  // overlays in dead regions:
  //  - pw/gw (k1): tri head — written pre-k0, read by k1, clobbered by k2.
  //  - wp/wg/c12 (k3): left head — written AFTER k2 (left dead), read by k3.
  ushort_t* pw_bf = tri;                 // 256*128
  ushort_t* gw_bf = tri + 32768;         // 256*128
  ushort_t* wp    = left;                // 128*128
  ushort_t* wg    = left + 16384;        // 128*128
  float2*   c12   = (float2*)(left + 32768);

  k_prep   <<<dim3(64),          dim3(256), 0, stream>>>(p_in_w, g_in_w, pw_bf, gw_bf, 8192, 8192);
  k0_ln_in <<<dim3(RTOT/4),      dim3(256), 0, stream>>>(pair, ln_in_w, ln_in_b, lnx);
  k1_inproj<<<dim3(4, RTOT/256), dim3(256), 0, stream>>>(lnx, pw_bf, gw_bf, left, right);
  k2_tri   <<<dim3(512),         dim3(256), 0, stream>>>(left, right, tri);
  k_prep2  <<<dim3(1),           dim3(256), 0, stream>>>(p_out_w, g_out_w, ln_out_w, ln_out_b, wp, wg, c12);
  k3_out   <<<dim3(RTOT/64),     dim3(256), 0, stream>>>(tri, lnx, wp, wg, c12, out);
}

// Round 4
// 448.804 us; speedup vs baseline: 1.1703x; 1.1703x over previous
//
#include <hip/hip_runtime.h>

#define NSEQ 512
#define RTOT (NSEQ*NSEQ)   // 262144 rows
#define DM 128

typedef unsigned short ushort_t;
using short8 = __attribute__((ext_vector_type(8))) short;
using f32x4  = __attribute__((ext_vector_type(4))) float;

__device__ __forceinline__ unsigned short f2bf(float x){
  union { float f; unsigned int u; } v; v.f = x;
  unsigned int r = v.u + 0x7fffu + ((v.u >> 16) & 1u);   // RNE
  return (unsigned short)(r >> 16);
}
__device__ __forceinline__ float bf2f(unsigned short u){
  union { unsigned int u; float f; } v; v.u = ((unsigned int)u) << 16;
  return v.f;
}
__device__ __forceinline__ unsigned int pack2(float a, float b){
  return (unsigned int)f2bf(a) | ((unsigned int)f2bf(b) << 16);
}
__device__ __forceinline__ float sigmoidf(float x){ return 1.0f/(1.0f + __expf(-x)); }

// -------- K_prep: one-shot fp32 -> bf16 conversion of k1 weights -----------
__global__ __launch_bounds__(256) void k_prep(const float* __restrict__ a,
                                              const float* __restrict__ b,
                                              ushort_t* __restrict__ da,
                                              ushort_t* __restrict__ db,
                                              int na4, int nb4){
  int idx = blockIdx.x*256 + threadIdx.x;
  const float* src; ushort_t* dst; int i;
  if (idx < na4){ src = a; dst = da; i = idx; }
  else { i = idx - na4; if (i >= nb4) return; src = b; dst = db; }
  float4 v = *(const float4*)(src + (size_t)i*4);
  uint2 pk; pk.x = pack2(v.x, v.y); pk.y = pack2(v.z, v.w);
  *(uint2*)(dst + (size_t)i*4) = pk;
}

// -------- K_prep2 (parallel): W'[h,d]=ln_out_w[d]*p_out_w[h,d] (bf16);
// c1[h]=sum_d bf16(W'); c2[h]=sum_d ln_out_b[d]*p_out_w[h,d]; wg=bf16(g_out_w).
__global__ __launch_bounds__(256) void k_prep2(const float* __restrict__ p_out_w,
                                               const float* __restrict__ g_out_w,
                                               const float* __restrict__ ln_out_w,
                                               const float* __restrict__ ln_out_b,
                                               ushort_t* __restrict__ wp,
                                               ushort_t* __restrict__ wg,
                                               float2* __restrict__ c12){
  int b = blockIdx.x, tid = threadIdx.x;
  if (b < 8){                                      // wg: 16384 elems, 8/thread
    int i = b*2048 + tid*8;
    float4 v0 = *(const float4*)&g_out_w[i];
    float4 v1 = *(const float4*)&g_out_w[i+4];
    uint2 p0; p0.x = pack2(v0.x, v0.y); p0.y = pack2(v0.z, v0.w);
    uint2 p1; p1.x = pack2(v1.x, v1.y); p1.y = pack2(v1.z, v1.w);
    *(uint2*)&wg[i]   = p0;
    *(uint2*)&wg[i+4] = p1;
  } else {                                         // wp + c12: wave per row
    int r = (b-8)*4 + (tid>>6), lane = tid & 63;
    float s1 = 0.f, s2 = 0.f;
    #pragma unroll
    for (int t = 0; t < 2; t++){
      int d = lane + t*64;
      float v = p_out_w[(size_t)r*DM + d];
      unsigned short h = f2bf(v * ln_out_w[d]);
      wp[(size_t)r*DM + d] = h;
      s1 += bf2f(h);
      s2 += ln_out_b[d] * v;
    }
    #pragma unroll
    for (int off = 32; off; off >>= 1){ s1 += __shfl_xor(s1, off); s2 += __shfl_xor(s2, off); }
    if (lane == 0) c12[r] = make_float2(s1, s2);
  }
}

// ---------------- K0: LayerNorm(pair) -> lnx bf16 [R][128] -----------------
__global__ __launch_bounds__(256) void k0_ln_in(const float* __restrict__ pair,
                                                const float* __restrict__ w,
                                                const float* __restrict__ b,
                                                ushort_t* __restrict__ lnx){
  int wv = threadIdx.x >> 6, lane = threadIdx.x & 63;
  size_t row = (size_t)blockIdx.x * 4 + wv;          // one wave per row
  const float2* src = (const float2*)(pair + row * DM);
  float2 v = src[lane];
  float s = v.x + v.y, s2 = v.x*v.x + v.y*v.y;
  #pragma unroll
  for (int off = 32; off; off >>= 1){ s += __shfl_xor(s, off); s2 += __shfl_xor(s2, off); }
  float mu = s * (1.f/DM);
  float rstd = rsqrtf(s2*(1.f/DM) - mu*mu + 1e-5f);
  float o0 = (v.x - mu)*rstd*w[2*lane]   + b[2*lane];
  float o1 = (v.y - mu)*rstd*w[2*lane+1] + b[2*lane+1];
  ((unsigned int*)(lnx + row * DM))[lane] = pack2(o0, o1);
}

// ------ K1: merged in-proj. One block = 128 rows x ALL 256 paired cols.
// lnx staged to LDS once (read exactly once from HBM); a-frags hoisted to
// registers; 4 weight groups (64 p-rows + 64 g-rows, L2-hot) staged per iter.
// left/right = sig(g)*p, stored d-major [128][RTOT].
__global__ __launch_bounds__(256) void k1_inproj(const ushort_t* __restrict__ lnx,
                                                 const ushort_t* __restrict__ pw_bf,
                                                 const ushort_t* __restrict__ gw_bf,
                                                 ushort_t* __restrict__ left,
                                                 ushort_t* __restrict__ right){
  __shared__ __align__(16) ushort_t A[128][136];
  __shared__ __align__(16) ushort_t B[128][136];   // rows 0:64 = p, 64:128 = g
  int tid = threadIdx.x;
  int w = tid >> 6, lane = tid & 63, m = lane & 15, quad = lane >> 4;
  int wr = w & 1;          // row half (64 rows)
  int wc = w >> 1;         // col half within group (32 cols)
  size_t row0 = (size_t)blockIdx.x * 128;

  #pragma unroll
  for (int it = 0; it < 8; it++){                  // stage A (fully coalesced)
    int e = (tid + it*256) * 8; int r = e >> 7, c = e & 127;
    *(uint4*)&A[r][c] = *(const uint4*)&lnx[(row0 + r)*DM + c];
  }
  __syncthreads();
  short8 a[4][4];                                  // [rt][k] hoisted once
  #pragma unroll
  for (int rt = 0; rt < 4; rt++)
    #pragma unroll
    for (int k = 0; k < 4; k++)
      a[rt][k] = *(const short8*)&A[wr*64 + rt*16 + m][k*32 + quad*8];

  for (int g = 0; g < 4; g++){
    __syncthreads();                               // protect prev group's B reads
    #pragma unroll
    for (int it = 0; it < 8; it++){                // stage B group (L2-hot)
      int e = (tid + it*256) * 8; int r = e >> 7, c = e & 127;
      const ushort_t* srcw = (r < 64) ? &pw_bf[(size_t)(g*64 + r)*DM + c]
                                      : &gw_bf[(size_t)(g*64 + r - 64)*DM + c];
      *(uint4*)&B[r][c] = *(const uint4*)srcw;
    }
    __syncthreads();

    f32x4 accp[4][2], accg[4][2];
    #pragma unroll
    for (int rt = 0; rt < 4; rt++)
      #pragma unroll
      for (int ct = 0; ct < 2; ct++){
        accp[rt][ct] = (f32x4){0.f,0.f,0.f,0.f};
        accg[rt][ct] = (f32x4){0.f,0.f,0.f,0.f};
      }
    #pragma unroll
    for (int k = 0; k < 4; k++){
      short8 bp[2], bg[2];
      #pragma unroll
      for (int ct = 0; ct < 2; ct++){
        bp[ct] = *(const short8*)&B[     wc*32 + ct*16 + m][k*32 + quad*8];
        bg[ct] = *(const short8*)&B[64 + wc*32 + ct*16 + m][k*32 + quad*8];
      }
      #pragma unroll
      for (int rt = 0; rt < 4; rt++){
        #pragma unroll
        for (int ct = 0; ct < 2; ct++){
          accp[rt][ct] = __builtin_amdgcn_mfma_f32_16x16x32_bf16(a[rt][k], bp[ct], accp[rt][ct], 0, 0, 0);
          accg[rt][ct] = __builtin_amdgcn_mfma_f32_16x16x32_bf16(a[rt][k], bg[ct], accg[rt][ct], 0, 0, 0);
        }
      }
    }
    // epilogue: p-row index = g*64 + wc*32 + ct*16 + m; <128 -> left, else right
    ushort_t* outp = (g < 2) ? left : right;
    int dbase = (g & 1) * 64 + wc*32;
    #pragma unroll
    for (int ct = 0; ct < 2; ct++){
      int d = dbase + ct*16 + m;
      #pragma unroll
      for (int rt = 0; rt < 4; rt++){
        uint2 pk;
        pk.x = pack2(sigmoidf(accg[rt][ct][0])*accp[rt][ct][0],
                     sigmoidf(accg[rt][ct][1])*accp[rt][ct][1]);
        pk.y = pack2(sigmoidf(accg[rt][ct][2])*accp[rt][ct][2],
                     sigmoidf(accg[rt][ct][3])*accp[rt][ct][3]);
        *(uint2*)&outp[(size_t)d * RTOT + row0 + wr*64 + rt*16 + quad*4] = pk;
      }
    }
  }
}

// ------- K2: per d-plane NT GEMM: tri[d][i][j] = sum_k L[i,k]R[j,k]/L ------
__global__ __launch_bounds__(256) void k2_tri(const ushort_t* __restrict__ left,
                                              const ushort_t* __restrict__ right,
                                              ushort_t* __restrict__ tri){
  __shared__ __align__(16) ushort_t As[128][72];
  __shared__ __align__(16) ushort_t Bs[128][72];
  int tid = threadIdx.x;
  int b = blockIdx.x;
  int d = b & 127, ti = b >> 7;
  const ushort_t* Ap = left  + (size_t)d * RTOT;
  const ushort_t* Bp = right + (size_t)d * RTOT;
  ushort_t* Cp = tri + (size_t)d * RTOT;
  int i0 = ti * 128;
  int w = tid >> 6, lane = tid & 63, m = lane & 15, quad = lane >> 4;
  int wr = w & 1, wc = w >> 1;

  for (int tj = 0; tj < 4; tj++){
    int j0 = tj * 128;
    f32x4 acc[16];
    #pragma unroll
    for (int x = 0; x < 16; x++) acc[x] = (f32x4){0.f,0.f,0.f,0.f};

    for (int kt = 0; kt < NSEQ; kt += 64){
      __syncthreads();
      #pragma unroll
      for (int it = 0; it < 4; it++){
        int e = (tid + it*256) * 8; int r = e >> 6, c = e & 63;
        *(uint4*)&As[r][c] = *(const uint4*)&Ap[(size_t)(i0 + r)*NSEQ + kt + c];
        *(uint4*)&Bs[r][c] = *(const uint4*)&Bp[(size_t)(j0 + r)*NSEQ + kt + c];
      }
      __syncthreads();
      #pragma unroll
      for (int kk = 0; kk < 64; kk += 32){
        short8 a[4], bb[4];
        #pragma unroll
        for (int t = 0; t < 4; t++) a[t]  = *(const short8*)&As[wr*64 + t*16 + m][kk + quad*8];
        #pragma unroll
        for (int c = 0; c < 4; c++) bb[c] = *(const short8*)&Bs[wc*64 + c*16 + m][kk + quad*8];
        #pragma unroll
        for (int t = 0; t < 4; t++){
          #pragma unroll
          for (int c = 0; c < 4; c++){
            acc[t*4+c] = __builtin_amdgcn_mfma_f32_16x16x32_bf16(a[t], bb[c], acc[t*4+c], 0, 0, 0);
          }
        }
      }
    }
    const float s = 1.f / (float)NSEQ;
    #pragma unroll
    for (int t = 0; t < 4; t++){
      #pragma unroll
      for (int c = 0; c < 4; c++){
        int col = j0 + wc*64 + c*16 + m;
        #pragma unroll
        for (int rr = 0; rr < 4; rr++){
          int row = i0 + wr*64 + t*16 + quad*4 + rr;
          Cp[(size_t)row * NSEQ + col] = f2bf(acc[t*4+c][rr] * s);
        }
      }
    }
  }
}

// --- K3: transpose tri^T chunk into LDS (stats in-flight), folded-LN GEMM
//     with W', plus gate GEMM on direct-global lnx frags. --------------------
__global__ __launch_bounds__(256) void k3_out(const ushort_t* __restrict__ tri,
                                              const ushort_t* __restrict__ lnx,
                                              const ushort_t* __restrict__ wp,
                                              const ushort_t* __restrict__ wg,
                                              const float2* __restrict__ c12,
                                              float* __restrict__ out){
  __shared__ __align__(16) ushort_t A1[64][136];   // raw tri^T rows
  __shared__ __align__(16) ushort_t Bt[64][136];   // weight chunk
  __shared__ float ss[64][4], sq[64][4];
  __shared__ float2 srow[64];
  __shared__ float2 c12s[128];
  int tid = threadIdx.x;
  size_t r0 = (size_t)blockIdx.x * 64;
  if (tid < 128) c12s[tid] = c12[tid];

  int j = tid & 63, wv = tid >> 6;
  {                                                // transpose + stats accumulate
    float fs = 0.f, fq = 0.f;
    #pragma unroll
    for (int g = 0; g < 4; g++){
      int oct = wv*4 + g;
      const ushort_t* src = tri + (size_t)(oct*8)*RTOT + r0 + j;
      short8 v;
      #pragma unroll
      for (int dd = 0; dd < 8; dd++){
        unsigned short u = src[(size_t)dd * RTOT];
        v[dd] = (short)u;
        float f = bf2f(u); fs += f; fq += f*f;
      }
      *(short8*)&A1[j][oct*8] = v;
    }
    ss[j][wv] = fs; sq[j][wv] = fq;
  }
  __syncthreads();
  if (tid < 64){
    float s = ss[tid][0]+ss[tid][1]+ss[tid][2]+ss[tid][3];
    float q = sq[tid][0]+sq[tid][1]+sq[tid][2]+sq[tid][3];
    float mu = s * (1.f/DM);
    float rstd = rsqrtf(q*(1.f/DM) - mu*mu + 1e-5f);
    srow[tid] = make_float2(mu, rstd);
  }
  __syncthreads();

  int lane = tid & 63, m = lane & 15, quad = lane >> 4;
  short8 a1[4], a2[4];
  #pragma unroll
  for (int k = 0; k < 4; k++){
    a1[k] = *(const short8*)&A1[wv*16 + m][k*32 + quad*8];
    a2[k] = *(const short8*)&lnx[(r0 + wv*16 + m)*DM + k*32 + quad*8];
  }
  float2 st[4];
  #pragma unroll
  for (int rr = 0; rr < 4; rr++) st[rr] = srow[wv*16 + quad*4 + rr];

  #pragma unroll
  for (int ch = 0; ch < 2; ch++){
    f32x4 accp[4], accg[4];
    #pragma unroll
    for (int i = 0; i < 4; i++){ accp[i] = (f32x4){0.f,0.f,0.f,0.f}; accg[i] = (f32x4){0.f,0.f,0.f,0.f}; }

    #pragma unroll
    for (int it = 0; it < 4; it++){                // Bt <- W' rows
      int e = (tid + it*256) * 8; int r = e >> 7, c = e & 127;
      *(uint4*)&Bt[r][c] = *(const uint4*)&wp[(size_t)(ch*64 + r)*DM + c];
    }
    __syncthreads();
    #pragma unroll
    for (int k = 0; k < 4; k++){
      #pragma unroll
      for (int c = 0; c < 4; c++){
        short8 bf = *(const short8*)&Bt[c*16 + m][k*32 + quad*8];
        accp[c] = __builtin_amdgcn_mfma_f32_16x16x32_bf16(a1[k], bf, accp[c], 0, 0, 0);
      }
    }
    __syncthreads();
    #pragma unroll
    for (int it = 0; it < 4; it++){                // Bt <- g_out rows
      int e = (tid + it*256) * 8; int r = e >> 7, c = e & 127;
      *(uint4*)&Bt[r][c] = *(const uint4*)&wg[(size_t)(ch*64 + r)*DM + c];
    }
    __syncthreads();
    #pragma unroll
    for (int k = 0; k < 4; k++){
      #pragma unroll
      for (int c = 0; c < 4; c++){
        short8 bf = *(const short8*)&Bt[c*16 + m][k*32 + quad*8];
        accg[c] = __builtin_amdgcn_mfma_f32_16x16x32_bf16(a2[k], bf, accg[c], 0, 0, 0);
      }
    }
    #pragma unroll
    for (int c = 0; c < 4; c++){
      int h = ch*64 + c*16 + m;
      float2 cc = c12s[h];
      #pragma unroll
      for (int rr = 0; rr < 4; rr++){
        float val = st[rr].y * (accp[c][rr] - st[rr].x * cc.x) + cc.y;
        out[(r0 + wv*16 + quad*4 + rr)*DM + h] = sigmoidf(accg[c][rr]) * val;
      }
    }
    __syncthreads();                               // protect Bt for next chunk
  }
}

extern "C" void kernel_launch(void* const* d_in, const int* in_sizes, int n_in,
                              void* d_out, int out_size, void* d_ws, size_t ws_size,
                              hipStream_t stream){
  const float* pair     = (const float*)d_in[0];
  const float* ln_in_w  = (const float*)d_in[1];
  const float* ln_in_b  = (const float*)d_in[2];
  const float* p_in_w   = (const float*)d_in[3];
  const float* g_in_w   = (const float*)d_in[4];
  const float* ln_out_w = (const float*)d_in[5];
  const float* ln_out_b = (const float*)d_in[6];
  const float* p_out_w  = (const float*)d_in[7];
  const float* g_out_w  = (const float*)d_in[8];
  float* out = (float*)d_out;

  const size_t plane = (size_t)RTOT * DM;          // 33.5M elems, 64 MB bf16
  ushort_t* lnx   = (ushort_t*)d_ws;
  ushort_t* left  = lnx   + plane;
  ushort_t* right = left  + plane;
  ushort_t* tri   = right + plane;                 // total 256 MB

  // overlays in dead regions:
  //  - pw/gw (k1): tri head — written pre-k0, read by k1, clobbered by k2.
  //  - wp/wg/c12 (k3): left head — written AFTER k2 (left dead), read by k3.
  ushort_t* pw_bf = tri;                 // 256*128
  ushort_t* gw_bf = tri + 32768;         // 256*128
  ushort_t* wp    = left;                // 128*128
  ushort_t* wg    = left + 16384;        // 128*128
  float2*   c12   = (float2*)(left + 32768);

  k_prep   <<<dim3(64),        dim3(256), 0, stream>>>(p_in_w, g_in_w, pw_bf, gw_bf, 8192, 8192);
  k0_ln_in <<<dim3(RTOT/4),    dim3(256), 0, stream>>>(pair, ln_in_w, ln_in_b, lnx);
  k1_inproj<<<dim3(RTOT/128),  dim3(256), 0, stream>>>(lnx, pw_bf, gw_bf, left, right);
  k2_tri   <<<dim3(512),       dim3(256), 0, stream>>>(left, right, tri);
  k_prep2  <<<dim3(40),        dim3(256), 0, stream>>>(p_out_w, g_out_w, ln_out_w, ln_out_b, wp, wg, c12);
  k3_out   <<<dim3(RTOT/64),   dim3(256), 0, stream>>>(tri, lnx, wp, wg, c12, out);
}